// Round 7
// baseline (25.521 us; speedup 1.0000x reference)
//
#include <hip/hip_runtime.h>

namespace fk {

typedef float f32x4 __attribute__((ext_vector_type(4)));

struct V3 { float x, y, z; };
struct M3 { V3 c0, c1, c2; };   // column-major 3x3

__device__ __forceinline__ V3 axpy(float a, V3 x, V3 y) {
    return V3{ fmaf(a, x.x, y.x), fmaf(a, x.y, y.y), fmaf(a, x.z, y.z) };
}
__device__ __forceinline__ V3 sc(float a, V3 x) { return V3{ a * x.x, a * x.y, a * x.z }; }

__device__ __forceinline__ M3 mulRx(const M3& R, float s, float c) {
    return M3{ R.c0,
               axpy(s,  R.c2, sc(c, R.c1)),
               axpy(-s, R.c1, sc(c, R.c2)) };
}
__device__ __forceinline__ M3 mulRy(const M3& R, float s, float c) {
    return M3{ axpy(-s, R.c2, sc(c, R.c0)),
               R.c1,
               axpy(s,  R.c0, sc(c, R.c2)) };
}

__device__ __forceinline__ void load_angles(f32x4 v[6], const float* __restrict__ angles,
                                            long long elem, int B) {
    if (elem < B) {
        const f32x4* ap = reinterpret_cast<const f32x4*>(angles + (size_t)elem * 24);
        #pragma unroll
        for (int m = 0; m < 6; ++m) v[m] = ap[m];
    }
}

// compute one element's 29 node positions (87 floats) into o[0..86]
__device__ __forceinline__ void compute_element(const f32x4 v[6], float* o) {
    float q[24];
    #pragma unroll
    for (int m = 0; m < 6; ++m) {
        q[m*4+0] = v[m].x; q[m*4+1] = v[m].y; q[m*4+2] = v[m].z; q[m*4+3] = v[m].w;
    }

    constexpr float MN[24] = {-0.523599f,-0.698132f,-0.349066f,0.f,0.f,0.f,-0.349066f,0.f,0.f,0.f,
                              -0.349066f,0.f,0.f,0.f,0.f,-0.349066f,0.f,0.f,0.f,
                              -1.0472f,0.f,-0.20944f,-0.698132f,0.f};
    constexpr float MX[24] = {0.174533f,0.488692f,0.349066f,1.5708f,1.5708f,1.5708f,0.349066f,1.5708f,1.5708f,1.5708f,
                              0.349066f,1.5708f,1.5708f,1.5708f,0.785398f,0.349066f,1.5708f,1.5708f,1.5708f,
                              1.0472f,1.22173f,0.20944f,0.698132f,1.5708f};
    float s[24], c[24];
    #pragma unroll
    for (int j = 0; j < 24; ++j) {
        float a = fminf(fmaxf(q[j], MN[j]), MX[j]);
        __sincosf(a, &s[j], &c[j]);
    }

    auto emit = [&](int node, V3 t) {
        o[node*3+0] = t.x; o[node*3+1] = t.y; o[node*3+2] = t.z;
    };

    M3 R0{ V3{c[0],0.f,-s[0]}, V3{0.f,1.f,0.f}, V3{s[0],0.f,c[0]} };
    emit(0, V3{0.f,0.f,0.f});
    M3 R1 = mulRx(R0, s[1], c[1]);
    V3 t1 = sc(0.034f, R0.c2);
    emit(1, t1);

    auto finger = [&](int n0, float sy, float cy,
                      float s1, float c1, float s2, float c2, float s3, float c3,
                      float bx, float bz) {
        M3 Ra = mulRy(R1, sy, cy);
        V3 ta = axpy(bx, R1.c0, axpy(bz, R1.c2, t1));
        emit(n0, ta);
        M3 Rb = mulRx(Ra, s1, c1);
        emit(n0+1, ta);
        V3 tc = axpy(0.045f, Rb.c2, ta);
        M3 Rc = mulRx(Rb, s2, c2);
        emit(n0+2, tc);
        V3 td = axpy(0.025f, Rc.c2, tc);
        M3 Rd = mulRx(Rc, s3, c3);
        emit(n0+3, td);
        emit(n0+4, axpy(0.026f, Rd.c2, td));
    };
    finger(2,   s[2],  c[2],  s[3],c[3],   s[4],c[4],   s[5],c[5],  -0.033f, 0.095f);
    finger(7,   s[6],  c[6],  s[7],c[7],   s[8],c[8],   s[9],c[9],  -0.011f, 0.099f);
    finger(12, -s[10], c[10], s[11],c[11], s[12],c[12], s[13],c[13], 0.011f, 0.095f);

    {   // little finger metacarpal: Rodrigues about u=(ux,0,uz)
        const float ux = 0.573576f, uz = -0.819152f;
        float omc = 1.f - c[14];
        float l00 = fmaf(omc * ux, ux, c[14]);
        float l10 = s[14] * uz;
        float l20 = omc * ux * uz;
        float l01 = -s[14] * uz;
        float l21 = s[14] * ux;
        float l02 = omc * ux * uz;
        float l12 = -s[14] * ux;
        float l22 = fmaf(omc * uz, uz, c[14]);
        M3 R17;
        R17.c0 = axpy(l20, R1.c2, axpy(l10,  R1.c1, sc(l00, R1.c0)));
        R17.c1 = axpy(l21, R1.c2, axpy(c[14],R1.c1, sc(l01, R1.c0)));
        R17.c2 = axpy(l22, R1.c2, axpy(l12,  R1.c1, sc(l02, R1.c0)));
        V3 t17 = axpy(0.033f, R1.c0, axpy(0.02071f, R1.c2, t1));
        emit(17, t17);
        V3 t18 = axpy(0.06579f, R17.c2, t17);
        M3 R18 = mulRy(R17, -s[15], c[15]);
        emit(18, t18);
        M3 R19 = mulRx(R18, s[16], c[16]);
        emit(19, t18);
        V3 t20 = axpy(0.045f, R19.c2, t18);
        M3 R20 = mulRx(R19, s[17], c[17]);
        emit(20, t20);
        V3 t21 = axpy(0.025f, R20.c2, t20);
        M3 R21 = mulRx(R20, s[18], c[18]);
        emit(21, t21);
        emit(22, axpy(0.026f, R21.c2, t21));
    }

    {   // thumb
        const float k = 0.70710678f;
        float m00 = -k * c[19], m10 = -s[19];
        float m01 =  k * s[19], m11 = -c[19];
        M3 R23;
        R23.c0 = axpy(m00, R1.c2, axpy(m10, R1.c1, sc(m00, R1.c0)));
        R23.c1 = axpy(m01, R1.c2, axpy(m11, R1.c1, sc(m01, R1.c0)));
        R23.c2 = axpy(k, R1.c2, sc(-k, R1.c0));
        V3 t23 = axpy(-0.034f, R1.c0, axpy(-0.0085f, R1.c1, axpy(0.029f, R1.c2, t1)));
        emit(23, t23);
        M3 R24 = mulRx(R23, -s[20], c[20]);
        emit(24, t23);
        V3 t25 = axpy(0.038f, R24.c2, t23);
        M3 R25 = mulRx(R24, s[21], c[21]);
        emit(25, t25);
        M3 R26 = mulRy(R25, -s[22], c[22]);
        emit(26, t25);
        V3 t27 = axpy(0.032f, R26.c2, t25);
        M3 R27;
        R27.c0 = sc(-1.f, R26.c1);
        R27.c1 = axpy(s[23],  R26.c2, sc(c[23], R26.c0));
        R27.c2 = axpy(-s[23], R26.c0, sc(c[23], R26.c2));
        emit(27, t27);
        emit(28, axpy(0.0275f, R27.c2, t27));
    }
}

// flush 32 elements' outputs (2784 floats = 696 float4, 11136 B contiguous)
__device__ __forceinline__ void flush_half(const float* lds, float* __restrict__ gout,
                                           int tid) {
    const f32x4* lsrc = reinterpret_cast<const f32x4*>(lds);
    f32x4* gdst = reinterpret_cast<f32x4*>(gout);
    #pragma unroll
    for (int m = 0; m < 10; ++m)
        __builtin_nontemporal_store(lsrc[m * 64 + tid], &gdst[m * 64 + tid]);
    if (tid < 56) __builtin_nontemporal_store(lsrc[640 + tid], &gdst[640 + tid]);
}

__device__ __forceinline__ void flush_half_guarded(const float* lds, float* __restrict__ out,
                                                   long long e0, int tid, int B) {
    const size_t limit = (size_t)B * 87;
    const size_t base = (size_t)e0 * 87;
    for (int m = 0; m < 44; ++m) {
        int f = m * 64 + tid;
        if (f < 2784 && base + f < limit)
            __builtin_nontemporal_store(lds[f], &out[base + f]);
    }
}

// One wave per block, one 64-elem slab per block, processed as two 32-elem
// halves through an 11.1 KB LDS buffer (vs 22.3 KB full-slab): doubles
// resident blocks/CU (7 -> ~12-14) to raise concurrent store-stream pressure.
// Exec-masked compute (half the lanes) issues the same instruction count but
// issue is far under the HBM budget, so the extra issue is free.
__global__ __launch_bounds__(64, 3) void fk_kernel(const float* __restrict__ angles,
                                                   float* __restrict__ out, int B) {
    __shared__ float lds[32 * 87];   // 11136 B
    const int tid = threadIdx.x;
    const long long s = blockIdx.x;          // slab of 64 elements
    const long long e = s * 64 + tid;        // this thread's element

    f32x4 a6[6];
    load_angles(a6, angles, e, B);

    // ---- half A: elements s*64 .. s*64+31 ----
    if (tid < 32 && e < B) compute_element(a6, lds + tid * 87);
    __syncthreads();
    if (s * 64 + 32 <= (long long)B)
        flush_half(lds, out + (size_t)s * 64 * 87, tid);
    else
        flush_half_guarded(lds, out, s * 64, tid, B);
    __syncthreads();

    // ---- half B: elements s*64+32 .. s*64+63 ----
    if (tid >= 32 && e < B) compute_element(a6, lds + (tid - 32) * 87);
    __syncthreads();
    if (s * 64 + 32 < (long long)B) {
        if (s * 64 + 64 <= (long long)B)
            flush_half(lds, out + ((size_t)s * 64 + 32) * 87, tid);
        else
            flush_half_guarded(lds, out, s * 64 + 32, tid, B);
    }
}

} // namespace fk

extern "C" void kernel_launch(void* const* d_in, const int* in_sizes, int n_in,
                              void* d_out, int out_size, void* d_ws, size_t ws_size,
                              hipStream_t stream) {
    const float* angles = (const float*)d_in[0];
    float* out = (float*)d_out;
    const int B = in_sizes[0] / 24;
    const int grid = (B + 63) / 64;          // one 64-elem slab per block
    fk::fk_kernel<<<grid, 64, 0, stream>>>(angles, out, B);
}

// Round 8
// 23.650 us; speedup vs baseline: 1.0791x; 1.0791x over previous
//
#include <hip/hip_runtime.h>

namespace fk {

typedef float f32x4 __attribute__((ext_vector_type(4)));

struct V3 { float x, y, z; };
struct M3 { V3 c0, c1, c2; };   // column-major 3x3

__device__ __forceinline__ V3 axpy(float a, V3 x, V3 y) {
    return V3{ fmaf(a, x.x, y.x), fmaf(a, x.y, y.y), fmaf(a, x.z, y.z) };
}
__device__ __forceinline__ V3 sc(float a, V3 x) { return V3{ a * x.x, a * x.y, a * x.z }; }

__device__ __forceinline__ M3 mulRx(const M3& R, float s, float c) {
    return M3{ R.c0,
               axpy(s,  R.c2, sc(c, R.c1)),
               axpy(-s, R.c1, sc(c, R.c2)) };
}
__device__ __forceinline__ M3 mulRy(const M3& R, float s, float c) {
    return M3{ axpy(-s, R.c2, sc(c, R.c0)),
               R.c1,
               axpy(s,  R.c0, sc(c, R.c2)) };
}

__device__ __forceinline__ void load_angles(f32x4 v[6], const float* __restrict__ angles,
                                            long long elem, int B) {
    if (elem < B) {
        const f32x4* ap = reinterpret_cast<const f32x4*>(angles + (size_t)elem * 24);
        #pragma unroll
        for (int m = 0; m < 6; ++m) v[m] = ap[m];
    }
}

// compute one element's 29 node positions (87 floats) into o[0..86]
__device__ __forceinline__ void compute_element(const f32x4 v[6], float* o) {
    float q[24];
    #pragma unroll
    for (int m = 0; m < 6; ++m) {
        q[m*4+0] = v[m].x; q[m*4+1] = v[m].y; q[m*4+2] = v[m].z; q[m*4+3] = v[m].w;
    }

    constexpr float MN[24] = {-0.523599f,-0.698132f,-0.349066f,0.f,0.f,0.f,-0.349066f,0.f,0.f,0.f,
                              -0.349066f,0.f,0.f,0.f,0.f,-0.349066f,0.f,0.f,0.f,
                              -1.0472f,0.f,-0.20944f,-0.698132f,0.f};
    constexpr float MX[24] = {0.174533f,0.488692f,0.349066f,1.5708f,1.5708f,1.5708f,0.349066f,1.5708f,1.5708f,1.5708f,
                              0.349066f,1.5708f,1.5708f,1.5708f,0.785398f,0.349066f,1.5708f,1.5708f,1.5708f,
                              1.0472f,1.22173f,0.20944f,0.698132f,1.5708f};
    float s[24], c[24];
    #pragma unroll
    for (int j = 0; j < 24; ++j) {
        float a = fminf(fmaxf(q[j], MN[j]), MX[j]);
        __sincosf(a, &s[j], &c[j]);
    }

    auto emit = [&](int node, V3 t) {
        o[node*3+0] = t.x; o[node*3+1] = t.y; o[node*3+2] = t.z;
    };

    M3 R0{ V3{c[0],0.f,-s[0]}, V3{0.f,1.f,0.f}, V3{s[0],0.f,c[0]} };
    emit(0, V3{0.f,0.f,0.f});
    M3 R1 = mulRx(R0, s[1], c[1]);
    V3 t1 = sc(0.034f, R0.c2);
    emit(1, t1);

    auto finger = [&](int n0, float sy, float cy,
                      float s1, float c1, float s2, float c2, float s3, float c3,
                      float bx, float bz) {
        M3 Ra = mulRy(R1, sy, cy);
        V3 ta = axpy(bx, R1.c0, axpy(bz, R1.c2, t1));
        emit(n0, ta);
        M3 Rb = mulRx(Ra, s1, c1);
        emit(n0+1, ta);
        V3 tc = axpy(0.045f, Rb.c2, ta);
        M3 Rc = mulRx(Rb, s2, c2);
        emit(n0+2, tc);
        V3 td = axpy(0.025f, Rc.c2, tc);
        M3 Rd = mulRx(Rc, s3, c3);
        emit(n0+3, td);
        emit(n0+4, axpy(0.026f, Rd.c2, td));
    };
    finger(2,   s[2],  c[2],  s[3],c[3],   s[4],c[4],   s[5],c[5],  -0.033f, 0.095f);
    finger(7,   s[6],  c[6],  s[7],c[7],   s[8],c[8],   s[9],c[9],  -0.011f, 0.099f);
    finger(12, -s[10], c[10], s[11],c[11], s[12],c[12], s[13],c[13], 0.011f, 0.095f);

    {   // little finger metacarpal: Rodrigues about u=(ux,0,uz)
        const float ux = 0.573576f, uz = -0.819152f;
        float omc = 1.f - c[14];
        float l00 = fmaf(omc * ux, ux, c[14]);
        float l10 = s[14] * uz;
        float l20 = omc * ux * uz;
        float l01 = -s[14] * uz;
        float l21 = s[14] * ux;
        float l02 = omc * ux * uz;
        float l12 = -s[14] * ux;
        float l22 = fmaf(omc * uz, uz, c[14]);
        M3 R17;
        R17.c0 = axpy(l20, R1.c2, axpy(l10,  R1.c1, sc(l00, R1.c0)));
        R17.c1 = axpy(l21, R1.c2, axpy(c[14],R1.c1, sc(l01, R1.c0)));
        R17.c2 = axpy(l22, R1.c2, axpy(l12,  R1.c1, sc(l02, R1.c0)));
        V3 t17 = axpy(0.033f, R1.c0, axpy(0.02071f, R1.c2, t1));
        emit(17, t17);
        V3 t18 = axpy(0.06579f, R17.c2, t17);
        M3 R18 = mulRy(R17, -s[15], c[15]);
        emit(18, t18);
        M3 R19 = mulRx(R18, s[16], c[16]);
        emit(19, t18);
        V3 t20 = axpy(0.045f, R19.c2, t18);
        M3 R20 = mulRx(R19, s[17], c[17]);
        emit(20, t20);
        V3 t21 = axpy(0.025f, R20.c2, t20);
        M3 R21 = mulRx(R20, s[18], c[18]);
        emit(21, t21);
        emit(22, axpy(0.026f, R21.c2, t21));
    }

    {   // thumb
        const float k = 0.70710678f;
        float m00 = -k * c[19], m10 = -s[19];
        float m01 =  k * s[19], m11 = -c[19];
        M3 R23;
        R23.c0 = axpy(m00, R1.c2, axpy(m10, R1.c1, sc(m00, R1.c0)));
        R23.c1 = axpy(m01, R1.c2, axpy(m11, R1.c1, sc(m01, R1.c0)));
        R23.c2 = axpy(k, R1.c2, sc(-k, R1.c0));
        V3 t23 = axpy(-0.034f, R1.c0, axpy(-0.0085f, R1.c1, axpy(0.029f, R1.c2, t1)));
        emit(23, t23);
        M3 R24 = mulRx(R23, -s[20], c[20]);
        emit(24, t23);
        V3 t25 = axpy(0.038f, R24.c2, t23);
        M3 R25 = mulRx(R24, s[21], c[21]);
        emit(25, t25);
        M3 R26 = mulRy(R25, -s[22], c[22]);
        emit(26, t25);
        V3 t27 = axpy(0.032f, R26.c2, t25);
        M3 R27;
        R27.c0 = sc(-1.f, R26.c1);
        R27.c1 = axpy(s[23],  R26.c2, sc(c[23], R26.c0));
        R27.c2 = axpy(-s[23], R26.c0, sc(c[23], R26.c2));
        emit(27, t27);
        emit(28, axpy(0.0275f, R27.c2, t27));
    }
}

// flush 32 elements' outputs (2784 floats = 696 float4, 11136 B contiguous)
__device__ __forceinline__ void flush_half(const float* lds, float* __restrict__ gout,
                                           int tid) {
    const f32x4* lsrc = reinterpret_cast<const f32x4*>(lds);
    f32x4* gdst = reinterpret_cast<f32x4*>(gout);
    #pragma unroll
    for (int m = 0; m < 10; ++m)
        __builtin_nontemporal_store(lsrc[m * 64 + tid], &gdst[m * 64 + tid]);
    if (tid < 56) __builtin_nontemporal_store(lsrc[640 + tid], &gdst[640 + tid]);
}

__device__ __forceinline__ void flush_half_guarded(const float* lds, float* __restrict__ out,
                                                   long long e0, int tid, int B) {
    const size_t limit = (size_t)B * 87;
    const size_t base = (size_t)e0 * 87;
    for (int m = 0; m < 44; ++m) {
        int f = m * 64 + tid;
        if (f < 2784 && base + f < limit)
            __builtin_nontemporal_store(lds[f], &out[base + f]);
    }
}

// One wave per block, ONE 32-element half-slab per block (grid doubled vs R5).
// Lanes 0-31 compute (exec-masked); all 64 lanes flush the 11136 B contiguous
// region with NT float4 stores. 11.1 KB LDS -> ~13-14 blocks/CU (2x R5's 7),
// doubling concurrent store-stream pressure. No VGPR cap (R7's spill suspect
// removed), single barrier, no serialized second half.
__global__ __launch_bounds__(64) void fk_kernel(const float* __restrict__ angles,
                                                float* __restrict__ out, int B) {
    __shared__ float lds[32 * 87];   // 11136 B
    const int tid = threadIdx.x;
    const long long e0 = (long long)blockIdx.x * 32;   // first element of half-slab

    if (tid < 32) {
        const long long e = e0 + tid;
        f32x4 a6[6];
        load_angles(a6, angles, e, B);
        if (e < B) compute_element(a6, lds + tid * 87);
    }
    __syncthreads();

    if (e0 + 32 <= (long long)B)
        flush_half(lds, out + (size_t)e0 * 87, tid);
    else
        flush_half_guarded(lds, out, e0, tid, B);
}

} // namespace fk

extern "C" void kernel_launch(void* const* d_in, const int* in_sizes, int n_in,
                              void* d_out, int out_size, void* d_ws, size_t ws_size,
                              hipStream_t stream) {
    const float* angles = (const float*)d_in[0];
    float* out = (float*)d_out;
    const int B = in_sizes[0] / 24;
    const int grid = (B + 31) / 32;          // one 32-elem half-slab per block
    fk::fk_kernel<<<grid, 64, 0, stream>>>(angles, out, B);
}